// Round 1
// baseline (815.166 us; speedup 1.0000x reference)
//
#include <hip/hip_runtime.h>

// out[r, c] = x[r, c] * ( (u[c] >= 0.1f) ? vec[c] / 0.9f : 0.0f )
// N_ROWS = 131072, DEPTH = 1024 (fp32). Pure memory-bound columnwise scale.
//
// Traffic: 512 MiB read + 512 MiB write = 1.074 GB -> ~170 us at 6.3 TB/s.
// This version: 4-row unroll (4 independent 16B loads in flight per lane),
// nontemporal load/store (streaming data, bypass cache retention),
// grid = 2048 (8 blocks/CU, full occupancy, 16 iterations per block).

constexpr int DEPTH   = 1024;
constexpr int N_ROWS  = 131072;
constexpr int BLOCK   = 256;           // 256 threads * float4 = 1024 cols = one row
constexpr int DEPTH4  = DEPTH / 4;     // 256 float4 per row
constexpr float P_DROP      = 0.1f;
constexpr float ONE_MINUS_P = 0.9f;
constexpr int UNROLL  = 4;             // rows per block per iteration
constexpr int GRID    = 2048;          // 8 blocks/CU on 256 CUs

typedef float f32x4 __attribute__((ext_vector_type(4)));

__global__ __launch_bounds__(BLOCK) void MMDropoutDiagonal_kernel(
    const float4* __restrict__ x,
    const float4* __restrict__ vec4,
    const float4* __restrict__ u4,
    float4* __restrict__ out)
{
    const int tid = threadIdx.x;       // 0..255 -> columns [tid*4, tid*4+4)

    // Per-thread dropout scale, computed once, reused across all rows.
    // vec/u are 4 KiB each -> normal cached loads.
    const float4 v  = vec4[tid];
    const float4 uu = u4[tid];
    f32x4 s;
    s.x = (uu.x >= P_DROP) ? (v.x / ONE_MINUS_P) : 0.0f;
    s.y = (uu.y >= P_DROP) ? (v.y / ONE_MINUS_P) : 0.0f;
    s.z = (uu.z >= P_DROP) ? (v.z / ONE_MINUS_P) : 0.0f;
    s.w = (uu.w >= P_DROP) ? (v.w / ONE_MINUS_P) : 0.0f;

    const f32x4* __restrict__ xv  = (const f32x4*)x;
    f32x4* __restrict__       ov  = (f32x4*)out;

    // Each iteration: UNROLL contiguous rows -> 4 independent nontemporal
    // loads issued back-to-back before any store (memory-level parallelism),
    // then 4 nontemporal stores. 131072 / (2048*4) = 16 iterations exactly.
    for (int row0 = blockIdx.x * UNROLL; row0 < N_ROWS; row0 += gridDim.x * UNROLL) {
        const size_t base = (size_t)row0 * DEPTH4 + tid;

        f32x4 a0 = __builtin_nontemporal_load(&xv[base + 0 * DEPTH4]);
        f32x4 a1 = __builtin_nontemporal_load(&xv[base + 1 * DEPTH4]);
        f32x4 a2 = __builtin_nontemporal_load(&xv[base + 2 * DEPTH4]);
        f32x4 a3 = __builtin_nontemporal_load(&xv[base + 3 * DEPTH4]);

        a0 *= s;
        a1 *= s;
        a2 *= s;
        a3 *= s;

        __builtin_nontemporal_store(a0, &ov[base + 0 * DEPTH4]);
        __builtin_nontemporal_store(a1, &ov[base + 1 * DEPTH4]);
        __builtin_nontemporal_store(a2, &ov[base + 2 * DEPTH4]);
        __builtin_nontemporal_store(a3, &ov[base + 3 * DEPTH4]);
    }
}

extern "C" void kernel_launch(void* const* d_in, const int* in_sizes, int n_in,
                              void* d_out, int out_size, void* d_ws, size_t ws_size,
                              hipStream_t stream) {
    const float4* x    = (const float4*)d_in[0];
    const float4* vec4 = (const float4*)d_in[1];
    const float4* u4   = (const float4*)d_in[2];
    float4* out        = (float4*)d_out;

    MMDropoutDiagonal_kernel<<<GRID, BLOCK, 0, stream>>>(x, vec4, u4, out);
}